// Round 8
// baseline (330.112 us; speedup 1.0000x reference)
//
#include <hip/hip_runtime.h>
#include <hip/hip_bf16.h>

// CRF forward (torchcrf, reduction='sum') on MI355X. T=512, B=256, K=128.
// Denominator: 511 sequential steps of s' = (s @ E) * exp(em_t), E = exp(trans).
// R4/R5 post-mortem: VGPR_Count pinned at 40 => allocator (default occupancy
// target) spills OR rematerializes the E column every step (scratch/L2 reload
// on the critical path; FETCH unchanged since scratch+trans are L2-resident;
// VALUBusy 28%). Fixes:
//   1) __launch_bounds__(512, 2): 2 waves/EU == our actual residency (8 waves,
//      1 block/CU) -> 256-VGPR allocator budget, E stays register-resident.
//   2) keep-alive empty asm with "+v" on all 16 f2 E-regs at loop entry:
//      forces simultaneous VGPR materialization, blocks remat-sinking of the
//      exp(trans) computation into the loop.
//   3) 4 independent f2 accumulators (FMA dep chain 8 -> 4).
// Else identical to the twice-validated (absmax=0.0) R5 kernel: linear domain,
// deferred renorm every 4 steps (publish pre-barrier / apply next step / fp64
// log acc / rcp eps telescopes), raw lgkmcnt-only barrier (em prefetch stays
// in flight across steps), skewed quarter replicas of s in LDS (bank-conflict
// free, measured 0), thread (j=tid>>2,q=tid&3) quarter-dot + intra-quad shfl
// combine, prefix-mask length L hoisted out of the loop.

#define TT 512
#define BB 256
#define KK 128
#define TB 32768  // BB*KK

typedef float f2 __attribute__((ext_vector_type(2)));

#if __has_builtin(__builtin_elementwise_fma)
#define FMA2(a, b, c) __builtin_elementwise_fma((a), (b), (c))
#else
static __device__ __forceinline__ f2 FMA2(f2 a, f2 b, f2 c) {
  f2 r; r.x = fmaf(a.x, b.x, c.x); r.y = fmaf(a.y, b.y, c.y); return r;
}
#endif

// Raw workgroup barrier: waits LDS ops only; leaves global (vmcnt) loads in flight.
#define HOT_BARRIER()                                    \
  do {                                                   \
    asm volatile("s_waitcnt lgkmcnt(0)" ::: "memory");   \
    __builtin_amdgcn_s_barrier();                        \
    asm volatile("" ::: "memory");                       \
  } while (0)

__global__ __launch_bounds__(512, 2) void crf_main(
    const float* __restrict__ em,               // [T,B,K]
    const int* __restrict__ tags_raw,           // int32 or int64 [T,B] (detected)
    const unsigned char* __restrict__ mask_raw, // bool bytes or int32 [T,B] (detected)
    const float* __restrict__ startt,           // [K]
    const float* __restrict__ endt,             // [K]
    const float* __restrict__ trans,            // [K,K]
    double* __restrict__ acc)                   // ws accumulator (memset 0)
{
  const int b = blockIdx.x;
  const int tid = threadIdx.x;
  const int j = tid >> 2;        // 0..127 output tag
  const int q = tid & 3;         // quarter of K_prev axis
  const int wid = tid >> 6;      // wave 0..7
  const int qown = j >> 5;       // which quad lane stores s[j]

  __shared__ __align__(16) float srep[2][144];   // skewed: quarter q at [q*36, q*36+32)
  __shared__ __align__(16) float wavesum[16];
  __shared__ int sflags[4];
  __shared__ unsigned char smask[TT];

  // ---- dtype detection ----
  // tags int64 (jax x64): odd int32 words all zero (tags<128). int32: random tags.
  {
    int wv = (tid < 64) ? tags_raw[2 * tid + 1] : 0;
    unsigned long long bal = __ballot(wv != 0);
    if (tid == 0) {
      sflags[0] = (bal == 0ull) ? 1 : 0;        // 1 => int64 tags
      sflags[1] = (mask_raw[1] != 0) ? 0 : 1;   // 1 => int32 mask
    }
  }
  __syncthreads();
  const bool tags64 = (sflags[0] != 0);
  const bool mask32 = (sflags[1] != 0);
  const int* mask_i = (const int*)mask_raw;

  auto get_tag = [&](int t) -> int {
    int idx = t * BB + b;
    return tags64 ? tags_raw[2 * idx] : tags_raw[idx];
  };

  // ---- mask column -> LDS (used only for numerator / prefix length L) ----
  {
    int idx = tid * BB + b;
    bool m = mask32 ? (mask_i[idx] != 0) : (mask_raw[idx] != 0);
    smask[tid] = m ? 1 : 0;
  }
  __syncthreads();

  // ---- numerator: gold path score (one t per thread; prefix-contiguous mask) ----
  float ncon = 0.f, mcnt = 0.f;
  {
    const int t = tid;
    int ct = get_tag(t);
    bool m = (smask[t] != 0);
    if (m) mcnt = 1.f;
    if (t == 0) {
      ncon = startt[ct] + em[(size_t)b * KK + ct];
    } else if (m) {
      int pt = get_tag(t - 1);
      ncon = trans[pt * KK + ct] + em[((size_t)t * BB + b) * KK + ct];
    }
  }
  #pragma unroll
  for (int mm = 1; mm < 64; mm <<= 1) {
    ncon += __shfl_xor(ncon, mm, 64);
    mcnt += __shfl_xor(mcnt, mm, 64);
  }
  if ((tid & 63) == 0) {
    wavesum[wid] = ncon;
    wavesum[8 + wid] = mcnt;
  }
  __syncthreads();
  float num_b = 0.f;                     // live only in tid 0
  if (tid == 0) {
    float ns = 0.f, ms = 0.f;
    #pragma unroll
    for (int wv = 0; wv < 8; ++wv) { ns += wavesum[wv]; ms += wavesum[8 + wv]; }
    int L = (int)(ms + 0.5f);
    num_b = ns + endt[get_tag(L - 1)];   // mask[0] always true
    sflags[2] = L;
  }

  // ---- denominator prologue: E quarter-column in NAMED float2 registers ----
  const int bi = q * 32;
  f2 cl0, ch0, cl1, ch1, cl2, ch2, cl3, ch3, cl4, ch4, cl5, ch5, cl6, ch6, cl7, ch7;
  {
    const float* tp0 = trans + (size_t)bi * KK + j;
#define INITC(n)                                        \
    cl##n.x = __expf(tp0[(4 * n + 0) * KK]);            \
    cl##n.y = __expf(tp0[(4 * n + 1) * KK]);            \
    ch##n.x = __expf(tp0[(4 * n + 2) * KK]);            \
    ch##n.y = __expf(tp0[(4 * n + 3) * KK]);
    INITC(0) INITC(1) INITC(2) INITC(3) INITC(4) INITC(5) INITC(6) INITC(7)
#undef INITC
  }
  // Keep-alive: force all 32 E values simultaneously live in VGPRs here, so the
  // compiler cannot sink/remat the exp(trans) computation into the hot loop.
  asm volatile("" : "+v"(cl0), "+v"(ch0), "+v"(cl1), "+v"(ch1),
                    "+v"(cl2), "+v"(ch2), "+v"(cl3), "+v"(ch3),
                    "+v"(cl4), "+v"(ch4), "+v"(cl5), "+v"(ch5),
                    "+v"(cl6), "+v"(ch6), "+v"(cl7), "+v"(ch7));

  const float* emb = em + (size_t)b * KK + j;
  float e0 = __expf(startt[j] + emb[0]);
  if (q == qown) srep[0][j + 4 * qown] = e0;

  // em pipeline: pex = exp(em[t]); e1..e5 = raw em[t+1..t+5]
  float pex = __expf(emb[(size_t)1 * TB]);
  float e1 = emb[(size_t)2 * TB];
  float e2 = emb[(size_t)3 * TB];
  float e3 = emb[(size_t)4 * TB];
  float e4 = emb[(size_t)5 * TB];
  float e5 = emb[(size_t)6 * TB];
  __syncthreads();
  const int L = sflags[2];

  int cur = 0;
  double Cacc = 0.0;                      // used only by tid 0

  for (int t = 1; t < L; ++t) {
    float ecur = pex;                     // exp(em[t]) ready (off critical path)
    pex = __expf(e1);
    e1 = e2; e2 = e3; e3 = e4; e4 = e5;
    int tp = t + 6; if (tp > TT - 1) tp = TT - 1;
    e5 = emb[(size_t)tp * TB];            // stays in flight across the raw barrier

    // quarter dot: sum_{i in [32q,32q+32)} s[i] * E[i][j]
    // 4 independent f2 accumulators: dep chain length 4 (was 8).
    const float4* sp = reinterpret_cast<const float4*>(&srep[cur][q * 36]);
    f2 p0 = {0.f, 0.f}, p1 = {0.f, 0.f}, p2 = {0.f, 0.f}, p3 = {0.f, 0.f};
#define DOTE(n)                                          \
    { float4 s4 = sp[n];                                 \
      f2 slo = {s4.x, s4.y}; f2 shi = {s4.z, s4.w};      \
      p0 = FMA2(slo, cl##n, p0);                         \
      p1 = FMA2(shi, ch##n, p1); }
#define DOTO(n)                                          \
    { float4 s4 = sp[n];                                 \
      f2 slo = {s4.x, s4.y}; f2 shi = {s4.z, s4.w};      \
      p2 = FMA2(slo, cl##n, p2);                         \
      p3 = FMA2(shi, ch##n, p3); }
    DOTE(0) DOTO(1) DOTE(2) DOTO(3) DOTE(4) DOTO(5) DOTE(6) DOTO(7)
#undef DOTE
#undef DOTO
    f2 ps = p0 + p1 + p2 + p3;
    float v = ps.x + ps.y;
    v += __shfl_xor(v, 1, 64);            // intra-quad combine (cheap)
    v += __shfl_xor(v, 2, 64);
    float w = v * ecur;

    if ((t & 3) == 1 && t != 1) {
      // apply deferred normalizer published at t-1 (read is post-barrier of t-1)
      float4 wa = *reinterpret_cast<const float4*>(&wavesum[0]);
      float4 wb = *reinterpret_cast<const float4*>(&wavesum[4]);
      float tot = ((wa.x + wa.y) + (wa.z + wa.w)) + ((wb.x + wb.y) + (wb.z + wb.w));
      if (tid == 0) Cacc += (double)__logf(tot);
      w *= __builtin_amdgcn_rcpf(tot);    // eps telescopes into next log window
    }
    if (q == qown) srep[cur ^ 1][j + 4 * qown] = w;
    if ((t & 3) == 0) {
      // publish partial sums for application at t+1 (pre-barrier write)
      float r = w;
      r += __shfl_xor(r, 4, 64);
      r += __shfl_xor(r, 8, 64);
      r += __shfl_xor(r, 16, 64);
      r += __shfl_xor(r, 32, 64);
      if ((tid & 63) == 0) wavesum[wid] = r;
    }
    HOT_BARRIER();                        // lgkmcnt only — vmcnt stays outstanding
    cur ^= 1;
  }

  // ---- final: den = Cacc + log(sum_j s[j]*exp(end[j])) ----
  float x = srep[cur][j + 4 * qown] * __expf(endt[j]);
  x += __shfl_xor(x, 4, 64);
  x += __shfl_xor(x, 8, 64);
  x += __shfl_xor(x, 16, 64);
  x += __shfl_xor(x, 32, 64);
  if ((tid & 63) == 0) wavesum[wid] = x;
  __syncthreads();
  if (tid == 0) {
    float tot = 0.f;
    #pragma unroll
    for (int wv = 0; wv < 8; ++wv) tot += wavesum[wv];
    double den = Cacc + (double)__logf(tot);
    atomicAdd(acc, (double)num_b - den);
  }
}

__global__ void crf_finalize(const double* __restrict__ acc, float* __restrict__ out) {
  out[0] = (float)acc[0];
}

extern "C" void kernel_launch(void* const* d_in, const int* in_sizes, int n_in,
                              void* d_out, int out_size, void* d_ws, size_t ws_size,
                              hipStream_t stream) {
  const float* em    = (const float*)d_in[0];
  const int*   tags  = (const int*)d_in[1];
  const unsigned char* mask = (const unsigned char*)d_in[2];
  const float* startt = (const float*)d_in[3];
  const float* endt   = (const float*)d_in[4];
  const float* trans  = (const float*)d_in[5];
  double* acc = (double*)d_ws;

  hipMemsetAsync(d_ws, 0, sizeof(double), stream);
  crf_main<<<256, 512, 0, stream>>>(em, tags, mask, startt, endt, trans, acc);
  crf_finalize<<<1, 1, 0, stream>>>(acc, (float*)d_out);
}

// Round 9
// 316.619 us; speedup vs baseline: 1.0426x; 1.0426x over previous
//
#include <hip/hip_runtime.h>
#include <hip/hip_bf16.h>

// CRF forward (torchcrf, reduction='sum') on MI355X. T=512, B=256, K=128.
// Denominator: 511 sequential steps of s' = (s @ E) * exp(em_t), E = exp(trans).
//
// R8 post-mortem: kernel is LDS-INSTRUCTION-THROUGHPUT-BOUND. Old topology
// (512 thr, 32i x 1j): 64 ds_read_b128 + ~16 ds_bpermute (shfl) + 8 writes
// ~= 88 LDS instrs/CU/step x ~12cy ~= 1050cy ~= measured 1220cy/step.
// Register fixes were invisible behind that wall (VALUBusy 29%).
//
// NEW TOPOLOGY (this round): 256 threads, thread (jp=tid>>2, o=tid&3) covers
// 32 i x 2 j. E held as 32 f2 regs (64 VGPR), pk-FMA pairs over j.
//   - LDS per CU per step: 4 waves x (8 ds_read_b128 + 1 ds_write_b64) = 36
//   - quad combine via explicit DPP quad_perm (VALU pipe, NOT ds_bpermute)
//   - renorm publish shuffles only every 4th step (amortized ~1 instr/step)
// Carried over (validated absmax=0.0 x3): linear domain, deferred renorm
// every 4 steps (publish pre-barrier / apply next step / fp64 log / rcp eps
// telescopes; totals carry a 0.25 factor for the quad replication), raw
// lgkmcnt-only barrier, 36-float skewed s slices (conflict-free, measured 0),
// prefix-mask length L hoisted, on-device dtype detection.

#define TT 512
#define BB 256
#define KK 128
#define TB 32768  // BB*KK

typedef float f2 __attribute__((ext_vector_type(2)));

#if __has_builtin(__builtin_elementwise_fma)
#define FMA2(a, b, c) __builtin_elementwise_fma((a), (b), (c))
#else
static __device__ __forceinline__ f2 FMA2(f2 a, f2 b, f2 c) {
  f2 r; r.x = fmaf(a.x, b.x, c.x); r.y = fmaf(a.y, b.y, c.y); return r;
}
#endif

// Quad-sum via DPP quad_perm (xor1 = 0xB1, xor2 = 0x4E): pure VALU.
static __device__ __forceinline__ float qsum4(float x) {
  x += __int_as_float(__builtin_amdgcn_update_dpp(
      0, __float_as_int(x), 0xB1, 0xF, 0xF, false));
  x += __int_as_float(__builtin_amdgcn_update_dpp(
      0, __float_as_int(x), 0x4E, 0xF, 0xF, false));
  return x;
}

// Raw workgroup barrier: waits LDS ops only; global loads stay in flight.
#define HOT_BARRIER()                                    \
  do {                                                   \
    asm volatile("s_waitcnt lgkmcnt(0)" ::: "memory");   \
    __builtin_amdgcn_s_barrier();                        \
    asm volatile("" ::: "memory");                       \
  } while (0)

__global__ __launch_bounds__(256, 1) void crf_main(
    const float* __restrict__ em,               // [T,B,K]
    const int* __restrict__ tags_raw,           // int32 or int64 [T,B] (detected)
    const unsigned char* __restrict__ mask_raw, // bool bytes or int32 [T,B] (detected)
    const float* __restrict__ startt,           // [K]
    const float* __restrict__ endt,             // [K]
    const float* __restrict__ trans,            // [K,K]
    double* __restrict__ acc)                   // ws accumulator (memset 0)
{
  const int b = blockIdx.x;
  const int tid = threadIdx.x;
  const int jp = tid >> 2;       // 0..63 : j-pair, covers j = 2jp, 2jp+1
  const int o = tid & 3;         // 0..3  : i-quarter, covers i in [32o, 32o+32)
  const int wid = tid >> 6;      // wave 0..3
  // s slice layout: quarter q at float offset 36q; s[idx] at 36*(idx>>5)+(idx&31)
  const int woff = 36 * (jp >> 4) + 2 * (jp & 15);

  __shared__ __align__(16) float srep[2][144];
  __shared__ __align__(16) float wavesum[16];
  __shared__ int sflags[4];
  __shared__ unsigned char smask[TT];

  // ---- dtype detection ----
  // tags int64 (jax x64): odd int32 words all zero (tags<128). int32: random tags.
  {
    int wv = (tid < 64) ? tags_raw[2 * tid + 1] : 0;
    unsigned long long bal = __ballot(wv != 0);
    if (tid == 0) {
      sflags[0] = (bal == 0ull) ? 1 : 0;        // 1 => int64 tags
      sflags[1] = (mask_raw[1] != 0) ? 0 : 1;   // 1 => int32 mask
    }
  }
  __syncthreads();
  const bool tags64 = (sflags[0] != 0);
  const bool mask32 = (sflags[1] != 0);
  const int* mask_i = (const int*)mask_raw;

  auto get_tag = [&](int t) -> int {
    int idx = t * BB + b;
    return tags64 ? tags_raw[2 * idx] : tags_raw[idx];
  };

  // ---- mask column -> LDS (numerator / prefix length L only) ----
  for (int t = tid; t < TT; t += 256) {
    int idx = t * BB + b;
    bool m = mask32 ? (mask_i[idx] != 0) : (mask_raw[idx] != 0);
    smask[t] = m ? 1 : 0;
  }
  __syncthreads();

  // ---- numerator: gold path score (prefix-contiguous mask) ----
  float ncon = 0.f, mcnt = 0.f;
  for (int t = tid; t < TT; t += 256) {
    int ct = get_tag(t);
    bool m = (smask[t] != 0);
    if (m) mcnt += 1.f;
    if (t == 0) {
      ncon += startt[ct] + em[(size_t)b * KK + ct];
    } else if (m) {
      int pt = get_tag(t - 1);
      ncon += trans[pt * KK + ct] + em[((size_t)t * BB + b) * KK + ct];
    }
  }
  #pragma unroll
  for (int mm = 1; mm < 64; mm <<= 1) {
    ncon += __shfl_xor(ncon, mm, 64);
    mcnt += __shfl_xor(mcnt, mm, 64);
  }
  if ((tid & 63) == 0) {
    wavesum[wid] = ncon;
    wavesum[8 + wid] = mcnt;
  }
  __syncthreads();
  float num_b = 0.f;                     // live only in tid 0
  if (tid == 0) {
    float ns = 0.f, ms = 0.f;
    #pragma unroll
    for (int wv = 0; wv < 4; ++wv) { ns += wavesum[wv]; ms += wavesum[8 + wv]; }
    int L = (int)(ms + 0.5f);
    num_b = ns + endt[get_tag(L - 1)];   // mask[0] always true
    sflags[2] = L;
  }

  // ---- E tile: 32 rows (i = 32o+n) x 2 cols (j = 2jp, 2jp+1) as f2 regs ----
  f2 c0,  c1,  c2,  c3,  c4,  c5,  c6,  c7,
     c8,  c9,  c10, c11, c12, c13, c14, c15,
     c16, c17, c18, c19, c20, c21, c22, c23,
     c24, c25, c26, c27, c28, c29, c30, c31;
  {
    const float* tp0 = trans + (size_t)(o * 32) * KK + 2 * jp;
#define INITC(n)                                            \
    { float2 tv = *(const float2*)(tp0 + (n) * KK);         \
      c##n.x = __expf(tv.x); c##n.y = __expf(tv.y); }
    INITC(0)  INITC(1)  INITC(2)  INITC(3)  INITC(4)  INITC(5)  INITC(6)  INITC(7)
    INITC(8)  INITC(9)  INITC(10) INITC(11) INITC(12) INITC(13) INITC(14) INITC(15)
    INITC(16) INITC(17) INITC(18) INITC(19) INITC(20) INITC(21) INITC(22) INITC(23)
    INITC(24) INITC(25) INITC(26) INITC(27) INITC(28) INITC(29) INITC(30) INITC(31)
#undef INITC
  }
  // Keep-alive: force all 64 E values live in VGPRs at loop entry.
  asm volatile("" : "+v"(c0),  "+v"(c1),  "+v"(c2),  "+v"(c3),
                    "+v"(c4),  "+v"(c5),  "+v"(c6),  "+v"(c7),
                    "+v"(c8),  "+v"(c9),  "+v"(c10), "+v"(c11),
                    "+v"(c12), "+v"(c13), "+v"(c14), "+v"(c15));
  asm volatile("" : "+v"(c16), "+v"(c17), "+v"(c18), "+v"(c19),
                    "+v"(c20), "+v"(c21), "+v"(c22), "+v"(c23),
                    "+v"(c24), "+v"(c25), "+v"(c26), "+v"(c27),
                    "+v"(c28), "+v"(c29), "+v"(c30), "+v"(c31));

  const float* emb = em + (size_t)b * KK + 2 * jp;   // this thread's j-pair column
  {
    float2 st = *(const float2*)(startt + 2 * jp);
    float2 e0 = *(const float2*)(emb);
    if (o == 0) {
      float2 s0 = {__expf(st.x + e0.x), __expf(st.y + e0.y)};
      *(float2*)&srep[0][woff] = s0;
    }
  }

  // em pipeline: pex = exp(em[t]) (f2, one step ahead); e1..e4 raw em[t+1..t+4]
  float2 er = *(const float2*)(emb + (size_t)1 * TB);
  f2 pex; pex.x = __expf(er.x); pex.y = __expf(er.y);
  float2 e1 = *(const float2*)(emb + (size_t)2 * TB);
  float2 e2 = *(const float2*)(emb + (size_t)3 * TB);
  float2 e3 = *(const float2*)(emb + (size_t)4 * TB);
  float2 e4 = *(const float2*)(emb + (size_t)5 * TB);
  __syncthreads();
  const int L = sflags[2];

  int cur = 0;
  double Cacc = 0.0;                      // used only by tid 0

  for (int t = 1; t < L; ++t) {
    f2 ecur = pex;
    pex.x = __expf(e1.x); pex.y = __expf(e1.y);
    e1 = e2; e2 = e3; e3 = e4;
    int tp = t + 5; if (tp > TT - 1) tp = TT - 1;
    e4 = *(const float2*)(emb + (size_t)tp * TB);   // in flight across barrier

    // partial dot over i in [32o, 32o+32) for both j's (pk-FMA), 4 accums
    const float4* sp = reinterpret_cast<const float4*>(&srep[cur][o * 36]);
    f2 a0 = {0.f, 0.f}, a1 = {0.f, 0.f}, a2 = {0.f, 0.f}, a3 = {0.f, 0.f};
#define DOTQ(m, cA, cB, cC, cD, accA, accB)              \
    { float4 s4 = sp[m];                                 \
      f2 v0 = {s4.x, s4.x}, v1 = {s4.y, s4.y};           \
      f2 v2 = {s4.z, s4.z}, v3 = {s4.w, s4.w};           \
      accA = FMA2(v0, cA, accA); accB = FMA2(v1, cB, accB); \
      accA = FMA2(v2, cC, accA); accB = FMA2(v3, cD, accB); }
    DOTQ(0, c0,  c1,  c2,  c3,  a0, a1)
    DOTQ(1, c4,  c5,  c6,  c7,  a2, a3)
    DOTQ(2, c8,  c9,  c10, c11, a0, a1)
    DOTQ(3, c12, c13, c14, c15, a2, a3)
    DOTQ(4, c16, c17, c18, c19, a0, a1)
    DOTQ(5, c20, c21, c22, c23, a2, a3)
    DOTQ(6, c24, c25, c26, c27, a0, a1)
    DOTQ(7, c28, c29, c30, c31, a2, a3)
#undef DOTQ
    f2 av = (a0 + a1) + (a2 + a3);
    // combine the 4 i-quarters within the quad: pure-VALU DPP
    f2 w;
    w.x = qsum4(av.x) * ecur.x;
    w.y = qsum4(av.y) * ecur.y;

    if ((t & 3) == 1 && t != 1) {
      // apply deferred normalizer published at t-1 (0.25: quad replication)
      float4 wa = *reinterpret_cast<const float4*>(&wavesum[0]);
      float tot = 0.25f * ((wa.x + wa.y) + (wa.z + wa.w));
      if (tid == 0) Cacc += (double)__logf(tot);
      float rt = __builtin_amdgcn_rcpf(tot);  // eps telescopes into next log
      w.x *= rt; w.y *= rt;
    }
    if (o == 0) {
      float2 ws = {w.x, w.y};
      *(float2*)&srep[cur ^ 1][woff] = ws;
    }
    if ((t & 3) == 0) {
      // publish partial sums (every lane in a quad holds the same pair)
      float r = w.x + w.y;
      r += __shfl_xor(r, 4, 64);
      r += __shfl_xor(r, 8, 64);
      r += __shfl_xor(r, 16, 64);
      r += __shfl_xor(r, 32, 64);
      if ((tid & 63) == 0) wavesum[wid] = r;
    }
    HOT_BARRIER();                        // lgkmcnt only — vmcnt outstanding
    cur ^= 1;
  }

  // ---- final: den = Cacc + log(0.25 * sum-over-quad-replicas) ----
  {
    float2 sv = *(const float2*)&srep[cur][woff];
    float2 ed = *(const float2*)(endt + 2 * jp);
    float x = sv.x * __expf(ed.x) + sv.y * __expf(ed.y);
    x += __shfl_xor(x, 4, 64);
    x += __shfl_xor(x, 8, 64);
    x += __shfl_xor(x, 16, 64);
    x += __shfl_xor(x, 32, 64);
    if ((tid & 63) == 0) wavesum[wid] = x;
  }
  __syncthreads();
  if (tid == 0) {
    float tot = 0.25f * (wavesum[0] + wavesum[1] + wavesum[2] + wavesum[3]);
    double den = Cacc + (double)__logf(tot);
    atomicAdd(acc, (double)num_b - den);
  }
}

__global__ void crf_finalize(const double* __restrict__ acc, float* __restrict__ out) {
  out[0] = (float)acc[0];
}

extern "C" void kernel_launch(void* const* d_in, const int* in_sizes, int n_in,
                              void* d_out, int out_size, void* d_ws, size_t ws_size,
                              hipStream_t stream) {
  const float* em    = (const float*)d_in[0];
  const int*   tags  = (const int*)d_in[1];
  const unsigned char* mask = (const unsigned char*)d_in[2];
  const float* startt = (const float*)d_in[3];
  const float* endt   = (const float*)d_in[4];
  const float* trans  = (const float*)d_in[5];
  double* acc = (double*)d_ws;

  hipMemsetAsync(d_ws, 0, sizeof(double), stream);
  crf_main<<<256, 256, 0, stream>>>(em, tags, mask, startt, endt, trans, acc);
  crf_finalize<<<1, 1, 0, stream>>>(acc, (float*)d_out);
}